// Round 6
// baseline (3656.829 us; speedup 1.0000x reference)
//
#include <hip/hip_runtime.h>
#include <hip/hip_bf16.h>
#include <math.h>

constexpr int BATCH = 32768;
constexpr int NI   = 32;    // N_INT
constexpr int OWND = 3;
constexpr int INTD = 7;
constexpr int AD   = 128;   // ATTN_D
constexpr int HIDN = 256;   // HID
constexpr int OUTD = 2;
constexpr int OBSD = OWND + NI * INTD;  // 227

__device__ __forceinline__ float lrelu(float x) { return x > 0.0f ? x : 0.2f * x; }

// One block (128 threads = 2 waves) per batch row. Thread t owns feature dim t.
// All inputs and the output are float32. Results go to `res` (either d_ws
// staging or d_out directly); a final copy kernel makes d_out's last writer
// deterministic and late (guards against post-write clobbering of d_out).
__global__ __launch_bounds__(AD) void fused_attn_sac(
    const float* __restrict__ obs,
    const float* __restrict__ own_W, const float* __restrict__ own_b,
    const float* __restrict__ int_W, const float* __restrict__ int_b,
    const float* __restrict__ Wq,    const float* __restrict__ Wk,
    const float* __restrict__ Wv,    const float* __restrict__ v_att,
    const float* __restrict__ proj_W,const float* __restrict__ proj_b,
    const float* __restrict__ h1_W,  const float* __restrict__ h1_b,
    const float* __restrict__ h2_W,  const float* __restrict__ h2_b,
    const float* __restrict__ out_W, const float* __restrict__ out_b,
    float* __restrict__ res)
{
    const int b    = blockIdx.x;
    const int t    = threadIdx.x;       // 0..127 == feature dim
    const int lane = t & 63;
    const int wid  = t >> 6;            // 0 or 1

    __shared__ __align__(16) float s_obs[OBSD + 1];
    __shared__ __align__(16) float s_ie[NI][AD];   // int_e (zero for padded), 16 KB
    __shared__ __align__(16) float s_own_e[AD];
    __shared__ float s_scoreP[NI][2];
    __shared__ float s_scores[NI];
    __shared__ float s_alpha[NI];
    __shared__ int   s_pad[NI];
    __shared__ __align__(16) float s_sv[AD];       // alpha @ int_e
    __shared__ __align__(16) float s_ctx[AD];
    __shared__ __align__(16) float s_x[HIDN];      // [own_e, attn_vec]
    __shared__ __align__(16) float s_h[HIDN];      // h1
    __shared__ float s_red[2][OUTD];

    // ---- stage obs row (f32) ----
    const float* orow = obs + (size_t)b * OBSD;
    for (int i = t; i < OBSD; i += AD) s_obs[i] = orow[i];
    __syncthreads();

    // ---- own_e (dim t) ----
    float oe = own_b[t];
    #pragma unroll
    for (int j = 0; j < OWND; j++) oe += s_obs[j] * own_W[j * AD + t];
    oe = lrelu(oe);
    s_own_e[t] = oe;

    // ---- padding flags (padded slots are exact zeros) ----
    if (t < NI) {
        float su = 0.f;
        #pragma unroll
        for (int j = 0; j < INTD; j++) su += fabsf(s_obs[OWND + t * INTD + j]);
        s_pad[t] = (su < 1e-6f) ? 1 : 0;
    }
    __syncthreads();   // s_pad + s_own_e visible

    // ---- int_e (zero rows for padded; padded rows contribute alpha=0 anyway) ----
    {
        float wi[INTD];
        #pragma unroll
        for (int j = 0; j < INTD; j++) wi[j] = int_W[j * AD + t];
        const float ib = int_b[t];
        for (int n = 0; n < NI; n++) {
            float z = ib;
            #pragma unroll
            for (int j = 0; j < INTD; j++) z += s_obs[OWND + n * INTD + j] * wi[j];
            s_ie[n][t] = s_pad[n] ? 0.0f : lrelu(z);
        }
    }

    // ---- q (dim t) ----
    float q = 0.f;
    for (int c = 0; c < AD; c += 4) {
        float4 f = *(const float4*)(s_own_e + c);
        q += f.x * Wq[(c + 0) * AD + t];
        q += f.y * Wq[(c + 1) * AD + t];
        q += f.z * Wq[(c + 2) * AD + t];
        q += f.w * Wq[(c + 3) * AD + t];
    }
    __syncthreads();   // s_ie complete

    // ---- k-projection, register-blocked: single pass over Wk ----
    float kv[NI];
    #pragma unroll
    for (int n = 0; n < NI; n++) kv[n] = 0.f;
    for (int c = 0; c < AD; c += 4) {
        const float w0 = Wk[(c + 0) * AD + t];
        const float w1 = Wk[(c + 1) * AD + t];
        const float w2 = Wk[(c + 2) * AD + t];
        const float w3 = Wk[(c + 3) * AD + t];
        #pragma unroll
        for (int n = 0; n < NI; n++) {
            float4 f = *(const float4*)(&s_ie[n][c]);   // LDS b128 broadcast
            kv[n] += f.x * w0 + f.y * w1 + f.z * w2 + f.w * w3;
        }
    }

    // ---- scores: reduce tanh(q+k)*va over 128 dims ----
    const float va = v_att[t];
    #pragma unroll
    for (int n = 0; n < NI; n++) {
        float p = tanhf(q + kv[n]) * va;
        #pragma unroll
        for (int off = 32; off >= 1; off >>= 1) p += __shfl_xor(p, off, 64);
        if (lane == 0) s_scoreP[n][wid] = p;
    }
    __syncthreads();

    // ---- softmax over interactions (-inf padding, nan_to_num) ----
    if (t < NI) {
        s_scores[t] = s_pad[t] ? -INFINITY : (s_scoreP[t][0] + s_scoreP[t][1]);
    }
    __syncthreads();
    if (t < NI) {
        float m = -INFINITY;
        for (int n = 0; n < NI; n++) m = fmaxf(m, s_scores[n]);
        float a = 0.f;
        if (!s_pad[t] && m > -INFINITY) {   // all-padded row => alpha = 0
            float denom = 0.f;
            for (int n = 0; n < NI; n++)
                if (!s_pad[n]) denom += expf(s_scores[n] - m);
            a = expf(s_scores[t] - m) / denom;
        }
        s_alpha[t] = a;
    }
    __syncthreads();

    // ---- ctx = (alpha @ int_e) @ Wv  (associativity: 32x cheaper) ----
    float sv = 0.f;
    for (int n = 0; n < NI; n++) sv += s_alpha[n] * s_ie[n][t];   // padded rows are 0
    s_sv[t] = sv;
    __syncthreads();
    float ctx = 0.f;
    for (int c = 0; c < AD; c += 4) {
        float4 f = *(const float4*)(s_sv + c);
        ctx += f.x * Wv[(c + 0) * AD + t];
        ctx += f.y * Wv[(c + 1) * AD + t];
        ctx += f.z * Wv[(c + 2) * AD + t];
        ctx += f.w * Wv[(c + 3) * AD + t];
    }
    s_ctx[t] = ctx;
    __syncthreads();

    // ---- attn_vec = tanh(ctx @ proj_W + proj_b) ----
    float av = proj_b[t];
    for (int c = 0; c < AD; c += 4) {
        float4 f = *(const float4*)(s_ctx + c);
        av += f.x * proj_W[(c + 0) * AD + t];
        av += f.y * proj_W[(c + 1) * AD + t];
        av += f.z * proj_W[(c + 2) * AD + t];
        av += f.w * proj_W[(c + 3) * AD + t];
    }
    av = tanhf(av);

    s_x[t] = oe;          // x = concat(own_e, attn_vec)
    s_x[AD + t] = av;
    __syncthreads();

    // ---- h1 (dims t, t+128) ----
    float h1a = h1_b[t], h1b = h1_b[t + AD];
    for (int c = 0; c < HIDN; c += 4) {
        float4 f = *(const float4*)(s_x + c);
        h1a += f.x * h1_W[(c + 0) * HIDN + t];
        h1a += f.y * h1_W[(c + 1) * HIDN + t];
        h1a += f.z * h1_W[(c + 2) * HIDN + t];
        h1a += f.w * h1_W[(c + 3) * HIDN + t];
        h1b += f.x * h1_W[(c + 0) * HIDN + t + AD];
        h1b += f.y * h1_W[(c + 1) * HIDN + t + AD];
        h1b += f.z * h1_W[(c + 2) * HIDN + t + AD];
        h1b += f.w * h1_W[(c + 3) * HIDN + t + AD];
    }
    s_h[t]      = lrelu(h1a);
    s_h[t + AD] = lrelu(h1b);
    __syncthreads();

    // ---- h2 (kept in registers) ----
    float h2a = h2_b[t], h2b = h2_b[t + AD];
    for (int c = 0; c < HIDN; c += 4) {
        float4 f = *(const float4*)(s_h + c);
        h2a += f.x * h2_W[(c + 0) * HIDN + t];
        h2a += f.y * h2_W[(c + 1) * HIDN + t];
        h2a += f.z * h2_W[(c + 2) * HIDN + t];
        h2a += f.w * h2_W[(c + 3) * HIDN + t];
        h2b += f.x * h2_W[(c + 0) * HIDN + t + AD];
        h2b += f.y * h2_W[(c + 1) * HIDN + t + AD];
        h2b += f.z * h2_W[(c + 2) * HIDN + t + AD];
        h2b += f.w * h2_W[(c + 3) * HIDN + t + AD];
    }
    h2a = lrelu(h2a);
    h2b = lrelu(h2b);

    // ---- out = h2 @ out_W + out_b  (block reduction over 256 hidden dims) ----
    float p0 = h2a * out_W[t * OUTD + 0] + h2b * out_W[(t + AD) * OUTD + 0];
    float p1 = h2a * out_W[t * OUTD + 1] + h2b * out_W[(t + AD) * OUTD + 1];
    #pragma unroll
    for (int off = 32; off >= 1; off >>= 1) {
        p0 += __shfl_xor(p0, off, 64);
        p1 += __shfl_xor(p1, off, 64);
    }
    if (lane == 0) { s_red[wid][0] = p0; s_red[wid][1] = p1; }
    __syncthreads();
    if (t == 0) {
        res[(size_t)b * OUTD + 0] = s_red[0][0] + s_red[1][0] + out_b[0];
        res[(size_t)b * OUTD + 1] = s_red[0][1] + s_red[1][1] + out_b[1];
    }
}

// Final copy: make d_out's last writer a dedicated, trivially-correct kernel
// that runs at the very end of the stream's work for this call.
__global__ __launch_bounds__(256) void copy_out(const float* __restrict__ src,
                                               float* __restrict__ dst, int n4) {
    int i = blockIdx.x * 256 + threadIdx.x;
    if (i < n4) ((float4*)dst)[i] = ((const float4*)src)[i];
}

extern "C" void kernel_launch(void* const* d_in, const int* in_sizes, int n_in,
                              void* d_out, int out_size, void* d_ws, size_t ws_size,
                              hipStream_t stream) {
    const float* obs    = (const float*)d_in[0];
    const float* own_W  = (const float*)d_in[1];
    const float* own_b  = (const float*)d_in[2];
    const float* int_W  = (const float*)d_in[3];
    const float* int_b  = (const float*)d_in[4];
    const float* Wq     = (const float*)d_in[5];
    const float* Wk     = (const float*)d_in[6];
    const float* Wv     = (const float*)d_in[7];
    const float* v_att  = (const float*)d_in[8];
    const float* proj_W = (const float*)d_in[9];
    const float* proj_b = (const float*)d_in[10];
    const float* h1_W   = (const float*)d_in[11];
    const float* h1_b   = (const float*)d_in[12];
    const float* h2_W   = (const float*)d_in[13];
    const float* h2_b   = (const float*)d_in[14];
    const float* out_W  = (const float*)d_in[15];
    const float* out_b  = (const float*)d_in[16];

    const size_t res_bytes = (size_t)BATCH * OUTD * sizeof(float);  // 256 KB
    const bool use_ws = (ws_size >= res_bytes);   // call-invariant -> same graph every call
    float* res = use_ws ? (float*)d_ws : (float*)d_out;

    fused_attn_sac<<<BATCH, AD, 0, stream>>>(
        obs, own_W, own_b, int_W, int_b, Wq, Wk, Wv, v_att,
        proj_W, proj_b, h1_W, h1_b, h2_W, h2_b, out_W, out_b, res);

    if (use_ws) {
        const int n4 = BATCH * OUTD / 4;          // 16384 float4s
        copy_out<<<(n4 + 255) / 256, 256, 0, stream>>>(res, (float*)d_out, n4);
    }
}

// Round 7
// 1696.686 us; speedup vs baseline: 2.1553x; 2.1553x over previous
//
#include <hip/hip_runtime.h>
#include <hip/hip_bf16.h>
#include <math.h>

constexpr int BATCH = 32768;
constexpr int NI   = 32;    // N_INT
constexpr int OWND = 3;
constexpr int INTD = 7;
constexpr int AD   = 128;   // ATTN_D
constexpr int HIDN = 256;   // HID
constexpr int OUTD = 2;
constexpr int OBSD = OWND + NI * INTD;  // 227

__device__ __forceinline__ float lrelu(float x) { return x > 0.0f ? x : 0.2f * x; }
// tanh via fast exp: exact at +-inf saturation, ~1e-6 abs error (budget 9.77e-3)
__device__ __forceinline__ float fast_tanh(float x) {
    float e = __expf(2.0f * x);
    return 1.0f - 2.0f / (e + 1.0f);
}

// One WAVE (64 lanes) per batch row; lane l owns feature dims (2l, 2l+1).
// Single-wave workgroup => LDS is wave-private => NO barriers anywhere.
__global__ __launch_bounds__(64) void fused_attn_sac(
    const float* __restrict__ obs,
    const float* __restrict__ own_W, const float* __restrict__ own_b,
    const float* __restrict__ int_W, const float* __restrict__ int_b,
    const float* __restrict__ Wq,    const float* __restrict__ Wk,
    const float* __restrict__ Wv,    const float* __restrict__ v_att,
    const float* __restrict__ proj_W,const float* __restrict__ proj_b,
    const float* __restrict__ h1_W,  const float* __restrict__ h1_b,
    const float* __restrict__ h2_W,  const float* __restrict__ h2_b,
    const float* __restrict__ out_W, const float* __restrict__ out_b,
    float* __restrict__ res)
{
    const int b  = blockIdx.x;
    const int l  = threadIdx.x;       // lane 0..63
    const int d0 = 2 * l;             // owned dims: d0, d0+1

    __shared__ __align__(16) float s_obs[OBSD + 1];
    __shared__ __align__(16) float s_ie[NI][AD];   // int_e, 16 KB
    __shared__ __align__(16) float s_own[AD];
    __shared__ __align__(16) float s_sv[AD];
    __shared__ __align__(16) float s_ctx[AD];
    __shared__ __align__(16) float s_x[HIDN];
    __shared__ __align__(16) float s_h[HIDN];

    // ---- stage obs row (wave-private, no barrier) ----
    const float* orow = obs + (size_t)b * OBSD;
    for (int i = l; i < OBSD; i += 64) s_obs[i] = orow[i];

    // ---- own_e (dims d0, d0+1) ----
    float2 ob = *(const float2*)(own_b + d0);
    float oe0 = ob.x, oe1 = ob.y;
    #pragma unroll
    for (int j = 0; j < OWND; j++) {
        float2 w = *(const float2*)(own_W + j * AD + d0);
        float x = s_obs[j];
        oe0 += x * w.x; oe1 += x * w.y;
    }
    oe0 = lrelu(oe0); oe1 = lrelu(oe1);
    *(float2*)(s_own + d0) = make_float2(oe0, oe1);

    // ---- int_e + pad bitmask (identical in every lane) ----
    unsigned pmask = 0u;
    {
        float wi0[INTD], wi1[INTD];
        #pragma unroll
        for (int j = 0; j < INTD; j++) {
            float2 w = *(const float2*)(int_W + j * AD + d0);
            wi0[j] = w.x; wi1[j] = w.y;
        }
        float2 ibv = *(const float2*)(int_b + d0);
        for (int n = 0; n < NI; n++) {
            float z0 = ibv.x, z1 = ibv.y, su = 0.f;
            #pragma unroll
            for (int j = 0; j < INTD; j++) {
                float x = s_obs[OWND + n * INTD + j];
                su += fabsf(x);
                z0 += x * wi0[j]; z1 += x * wi1[j];
            }
            if (su < 1e-6f) pmask |= (1u << n);
            *(float2*)(&s_ie[n][d0]) = make_float2(lrelu(z0), lrelu(z1));
        }
    }

    // ---- q (dims d0, d0+1) ----
    float q0 = 0.f, q1 = 0.f;
    #pragma unroll 2
    for (int c = 0; c < AD; c += 4) {
        float4 f = *(const float4*)(s_own + c);
        float2 a0 = *(const float2*)(Wq + (c + 0) * AD + d0);
        float2 a1 = *(const float2*)(Wq + (c + 1) * AD + d0);
        float2 a2 = *(const float2*)(Wq + (c + 2) * AD + d0);
        float2 a3 = *(const float2*)(Wq + (c + 3) * AD + d0);
        q0 += f.x * a0.x + f.y * a1.x + f.z * a2.x + f.w * a3.x;
        q1 += f.x * a0.y + f.y * a1.y + f.z * a2.y + f.w * a3.y;
    }

    // ---- k-projection: 32 interaction accumulators x 2 dims in registers,
    //      one pass over Wk; 8 FMAs per broadcast ds_read_b128 ----
    float kx[NI], ky[NI];
    #pragma unroll
    for (int n = 0; n < NI; n++) { kx[n] = 0.f; ky[n] = 0.f; }
    #pragma unroll 2
    for (int c = 0; c < AD; c += 4) {
        float2 a0 = *(const float2*)(Wk + (c + 0) * AD + d0);
        float2 a1 = *(const float2*)(Wk + (c + 1) * AD + d0);
        float2 a2 = *(const float2*)(Wk + (c + 2) * AD + d0);
        float2 a3 = *(const float2*)(Wk + (c + 3) * AD + d0);
        #pragma unroll
        for (int n = 0; n < NI; n++) {
            float4 f = *(const float4*)(&s_ie[n][c]);
            kx[n] += f.x * a0.x + f.y * a1.x + f.z * a2.x + f.w * a3.x;
            ky[n] += f.x * a0.y + f.y * a1.y + f.z * a2.y + f.w * a3.y;
        }
    }

    // ---- scores (butterfly leaves the sum in ALL lanes) ----
    float2 vav = *(const float2*)(v_att + d0);
    float sc[NI];
    #pragma unroll
    for (int n = 0; n < NI; n++) {
        float p = vav.x * fast_tanh(q0 + kx[n]) + vav.y * fast_tanh(q1 + ky[n]);
        #pragma unroll
        for (int off = 32; off >= 1; off >>= 1) p += __shfl_xor(p, off, 64);
        sc[n] = p;
    }

    // ---- masked softmax + nan_to_num, fully in registers (lane-redundant) ----
    float m = -INFINITY;
    #pragma unroll
    for (int n = 0; n < NI; n++) if (!((pmask >> n) & 1)) m = fmaxf(m, sc[n]);
    const bool anyv = (pmask != 0xFFFFFFFFu);
    float alpha[NI]; float den = 0.f;
    #pragma unroll
    for (int n = 0; n < NI; n++) {
        float e = (((pmask >> n) & 1) || !anyv) ? 0.f : __expf(sc[n] - m);
        alpha[n] = e; den += e;
    }
    float rden = anyv ? 1.0f / den : 0.0f;   // den >= 1 when anyv
    #pragma unroll
    for (int n = 0; n < NI; n++) alpha[n] *= rden;

    // ---- sv = alpha @ int_e (assoc: ctx = sv @ Wv) ----
    float sv0 = 0.f, sv1 = 0.f;
    #pragma unroll
    for (int n = 0; n < NI; n++) {
        float2 ie = *(const float2*)(&s_ie[n][d0]);
        sv0 += alpha[n] * ie.x; sv1 += alpha[n] * ie.y;
    }
    *(float2*)(s_sv + d0) = make_float2(sv0, sv1);

    // ---- ctx = sv @ Wv ----
    float c0 = 0.f, c1 = 0.f;
    #pragma unroll 2
    for (int c = 0; c < AD; c += 4) {
        float4 f = *(const float4*)(s_sv + c);
        float2 a0 = *(const float2*)(Wv + (c + 0) * AD + d0);
        float2 a1 = *(const float2*)(Wv + (c + 1) * AD + d0);
        float2 a2 = *(const float2*)(Wv + (c + 2) * AD + d0);
        float2 a3 = *(const float2*)(Wv + (c + 3) * AD + d0);
        c0 += f.x * a0.x + f.y * a1.x + f.z * a2.x + f.w * a3.x;
        c1 += f.x * a0.y + f.y * a1.y + f.z * a2.y + f.w * a3.y;
    }
    *(float2*)(s_ctx + d0) = make_float2(c0, c1);

    // ---- attn_vec = tanh(ctx @ proj_W + proj_b) ----
    float2 pb = *(const float2*)(proj_b + d0);
    float av0 = pb.x, av1 = pb.y;
    #pragma unroll 2
    for (int c = 0; c < AD; c += 4) {
        float4 f = *(const float4*)(s_ctx + c);
        float2 a0 = *(const float2*)(proj_W + (c + 0) * AD + d0);
        float2 a1 = *(const float2*)(proj_W + (c + 1) * AD + d0);
        float2 a2 = *(const float2*)(proj_W + (c + 2) * AD + d0);
        float2 a3 = *(const float2*)(proj_W + (c + 3) * AD + d0);
        av0 += f.x * a0.x + f.y * a1.x + f.z * a2.x + f.w * a3.x;
        av1 += f.x * a0.y + f.y * a1.y + f.z * a2.y + f.w * a3.y;
    }
    av0 = fast_tanh(av0); av1 = fast_tanh(av1);
    *(float2*)(s_x + d0)      = make_float2(oe0, oe1);
    *(float2*)(s_x + AD + d0) = make_float2(av0, av1);

    // ---- h1: lane owns hidden dims d0, d0+1, 128+d0, 128+d0+1 ----
    float2 b0 = *(const float2*)(h1_b + d0);
    float2 b1 = *(const float2*)(h1_b + AD + d0);
    float hA = b0.x, hB = b0.y, hC = b1.x, hD = b1.y;
    #pragma unroll 2
    for (int c = 0; c < HIDN; c += 4) {
        float4 f = *(const float4*)(s_x + c);
        #pragma unroll
        for (int i = 0; i < 4; i++) {
            float xf = (i == 0) ? f.x : (i == 1) ? f.y : (i == 2) ? f.z : f.w;
            float2 wA = *(const float2*)(h1_W + (c + i) * HIDN + d0);
            float2 wB = *(const float2*)(h1_W + (c + i) * HIDN + AD + d0);
            hA += xf * wA.x; hB += xf * wA.y; hC += xf * wB.x; hD += xf * wB.y;
        }
    }
    *(float2*)(s_h + d0)      = make_float2(lrelu(hA), lrelu(hB));
    *(float2*)(s_h + AD + d0) = make_float2(lrelu(hC), lrelu(hD));

    // ---- h2 (results kept in registers) ----
    float2 e0 = *(const float2*)(h2_b + d0);
    float2 e1 = *(const float2*)(h2_b + AD + d0);
    float rA = e0.x, rB = e0.y, rC = e1.x, rD = e1.y;
    #pragma unroll 2
    for (int c = 0; c < HIDN; c += 4) {
        float4 f = *(const float4*)(s_h + c);
        #pragma unroll
        for (int i = 0; i < 4; i++) {
            float xf = (i == 0) ? f.x : (i == 1) ? f.y : (i == 2) ? f.z : f.w;
            float2 wA = *(const float2*)(h2_W + (c + i) * HIDN + d0);
            float2 wB = *(const float2*)(h2_W + (c + i) * HIDN + AD + d0);
            rA += xf * wA.x; rB += xf * wA.y; rC += xf * wB.x; rD += xf * wB.y;
        }
    }
    rA = lrelu(rA); rB = lrelu(rB); rC = lrelu(rC); rD = lrelu(rD);

    // ---- out = h2 @ out_W + out_b ----
    float4 wo0 = *(const float4*)(out_W + (size_t)d0 * OUTD);         // rows d0, d0+1
    float4 wo1 = *(const float4*)(out_W + (size_t)(AD + d0) * OUTD);  // rows 128+d0, 128+d0+1
    float o0 = rA * wo0.x + rB * wo0.z + rC * wo1.x + rD * wo1.z;
    float o1 = rA * wo0.y + rB * wo0.w + rC * wo1.y + rD * wo1.w;
    #pragma unroll
    for (int off = 32; off >= 1; off >>= 1) {
        o0 += __shfl_xor(o0, off, 64);
        o1 += __shfl_xor(o1, off, 64);
    }
    if (l == 0) {
        *(float2*)(res + (size_t)b * OUTD) = make_float2(o0 + out_b[0], o1 + out_b[1]);
    }
}

// Final copy: d_out's last writer is this trivial kernel at the end of the
// stream (fixes the post-timing d_out clobber seen in R5 — do not remove).
__global__ __launch_bounds__(256) void copy_out(const float* __restrict__ src,
                                               float* __restrict__ dst, int n4) {
    int i = blockIdx.x * 256 + threadIdx.x;
    if (i < n4) ((float4*)dst)[i] = ((const float4*)src)[i];
}

extern "C" void kernel_launch(void* const* d_in, const int* in_sizes, int n_in,
                              void* d_out, int out_size, void* d_ws, size_t ws_size,
                              hipStream_t stream) {
    const float* obs    = (const float*)d_in[0];
    const float* own_W  = (const float*)d_in[1];
    const float* own_b  = (const float*)d_in[2];
    const float* int_W  = (const float*)d_in[3];
    const float* int_b  = (const float*)d_in[4];
    const float* Wq     = (const float*)d_in[5];
    const float* Wk     = (const float*)d_in[6];
    const float* Wv     = (const float*)d_in[7];
    const float* v_att  = (const float*)d_in[8];
    const float* proj_W = (const float*)d_in[9];
    const float* proj_b = (const float*)d_in[10];
    const float* h1_W   = (const float*)d_in[11];
    const float* h1_b   = (const float*)d_in[12];
    const float* h2_W   = (const float*)d_in[13];
    const float* h2_b   = (const float*)d_in[14];
    const float* out_W  = (const float*)d_in[15];
    const float* out_b  = (const float*)d_in[16];

    const size_t res_bytes = (size_t)BATCH * OUTD * sizeof(float);  // 256 KB
    const bool use_ws = (ws_size >= res_bytes);   // call-invariant
    float* res = use_ws ? (float*)d_ws : (float*)d_out;

    fused_attn_sac<<<BATCH, 64, 0, stream>>>(
        obs, own_W, own_b, int_W, int_b, Wq, Wk, Wv, v_att,
        proj_W, proj_b, h1_W, h1_b, h2_W, h2_b, out_W, out_b, res);

    if (use_ws) {
        const int n4 = BATCH * OUTD / 4;
        copy_out<<<(n4 + 255) / 256, 256, 0, stream>>>(res, (float*)d_out, n4);
    }
}